// Round 4
// baseline (714.657 us; speedup 1.0000x reference)
//
#include <hip/hip_runtime.h>
#include <cstdint>
#include <cstddef>

// ---------------- small utility kernels ----------------

__global__ void k_zero(int* __restrict__ p, int n) {
    int i = blockIdx.x * blockDim.x + threadIdx.x;
    if (i < n) p[i] = 0;
}

// ---------------- exclusive scan (3 kernels) ----------------

__global__ void k_scan1(const int* __restrict__ deg, int* __restrict__ rowptr,
                        int* __restrict__ bsum, int N) {
    __shared__ int s[256];
    int t = threadIdx.x;
    int i = blockIdx.x * 256 + t;
    int v = (i < N) ? deg[i] : 0;
    s[t] = v;
    __syncthreads();
    for (int off = 1; off < 256; off <<= 1) {
        int add = (t >= off) ? s[t - off] : 0;
        __syncthreads();
        s[t] += add;
        __syncthreads();
    }
    if (i < N) rowptr[i] = s[t] - v;           // exclusive within block
    if (t == 255) bsum[blockIdx.x] = s[255];   // block total
}

__global__ void k_scan2(int* __restrict__ bsum, int nb) {
    __shared__ int s[512];
    int t = threadIdx.x;
    int v = (t < nb) ? bsum[t] : 0;
    s[t] = v;
    __syncthreads();
    for (int off = 1; off < 512; off <<= 1) {
        int add = (t >= off) ? s[t - off] : 0;
        __syncthreads();
        s[t] += add;
        __syncthreads();
    }
    if (t < nb) bsum[t] = s[t] - v;            // exclusive block offsets
}

// scan3 + dinv fused
__global__ void k_scan3(int* __restrict__ rowptr, const int* __restrict__ bsum,
                        const int* __restrict__ deg, float* __restrict__ dinv,
                        int N, int E) {
    int i = blockIdx.x * 256 + threadIdx.x;
    if (i < N) {
        rowptr[i] += bsum[blockIdx.x];
        dinv[i] = rsqrtf((float)(deg[i] + 1));   // +1 = self-loop
    }
    if (i == 0) rowptr[N] = E;
}

// ---------------- role bodies for the fused dispatches ----------------

// GEMM1 tile: h1[row0:row0+64, 0:64] = x[.,512] @ W1[512,64]
__device__ __forceinline__ void gemm1_body(const float* __restrict__ x,
                                           const float* __restrict__ W1,
                                           float* __restrict__ h1,
                                           int row0, int N) {
    __shared__ float xsT[32][68];   // [kk][row], stride 68 keeps float4 aligned
    __shared__ float ws[32][64];    // [kk][col]
    int t = threadIdx.x;
    int tc = t & 15;        // col group (4 cols)
    int tr = t >> 4;        // row group (4 rows)

    float acc[4][4] = {{0.f}};

    int lr  = t >> 2;        // staging row 0..63
    int lkq = (t & 3) * 8;   // staging k offset (8 floats)

    for (int k0 = 0; k0 < 512; k0 += 32) {
        {
            int gr = row0 + lr;
            float4 v0 = {0.f, 0.f, 0.f, 0.f}, v1 = {0.f, 0.f, 0.f, 0.f};
            if (gr < N) {
                const float* p = x + (size_t)gr * 512 + k0 + lkq;
                v0 = *(const float4*)p;
                v1 = *(const float4*)(p + 4);
            }
            xsT[lkq + 0][lr] = v0.x; xsT[lkq + 1][lr] = v0.y;
            xsT[lkq + 2][lr] = v0.z; xsT[lkq + 3][lr] = v0.w;
            xsT[lkq + 4][lr] = v1.x; xsT[lkq + 5][lr] = v1.y;
            xsT[lkq + 6][lr] = v1.z; xsT[lkq + 7][lr] = v1.w;
        }
        {
            const float* p = W1 + (size_t)k0 * 64 + t * 8;
            float4 v0 = *(const float4*)p;
            float4 v1 = *(const float4*)(p + 4);
            int kk = (t * 8) >> 6;
            int cc = (t * 8) & 63;
            *(float4*)&ws[kk][cc]     = v0;
            *(float4*)&ws[kk][cc + 4] = v1;
        }
        __syncthreads();

#pragma unroll
        for (int kk = 0; kk < 32; ++kk) {
            float4 a = *(const float4*)&xsT[kk][tr * 4];
            float4 b = *(const float4*)&ws[kk][tc * 4];
            acc[0][0] += a.x * b.x; acc[0][1] += a.x * b.y;
            acc[0][2] += a.x * b.z; acc[0][3] += a.x * b.w;
            acc[1][0] += a.y * b.x; acc[1][1] += a.y * b.y;
            acc[1][2] += a.y * b.z; acc[1][3] += a.y * b.w;
            acc[2][0] += a.z * b.x; acc[2][1] += a.z * b.y;
            acc[2][2] += a.z * b.z; acc[2][3] += a.z * b.w;
            acc[3][0] += a.w * b.x; acc[3][1] += a.w * b.y;
            acc[3][2] += a.w * b.z; acc[3][3] += a.w * b.w;
        }
        __syncthreads();
    }

#pragma unroll
    for (int r = 0; r < 4; ++r) {
        int gr = row0 + tr * 4 + r;
        if (gr < N) {
            float4 v = {acc[r][0], acc[r][1], acc[r][2], acc[r][3]};
            *(float4*)&h1[(size_t)gr * 64 + tc * 4] = v;
        }
    }
}

// degree count, 4 edges/thread; returned old value = intra-row rank
__device__ __forceinline__ void deg_body(const int* __restrict__ dst,
                                         int* __restrict__ deg,
                                         int* __restrict__ rank,
                                         int blk, int E) {
    int base = blk * 1024 + (int)threadIdx.x;
#pragma unroll
    for (int j = 0; j < 4; ++j) {
        int e = base + j * 256;
        if (e < E) rank[e] = atomicAdd(&deg[dst[e]], 1);
    }
}

// atomic-free scatter, 4 edges/thread
__device__ __forceinline__ void scatter_body(const int* __restrict__ src,
                                             const int* __restrict__ dst,
                                             const int* __restrict__ rank,
                                             const int* __restrict__ rowptr,
                                             const float* __restrict__ dinv,
                                             int2* __restrict__ csr_sw,
                                             int blk, int E) {
    int base = blk * 1024 + (int)threadIdx.x;
#pragma unroll
    for (int j = 0; j < 4; ++j) {
        int e = base + j * 256;
        if (e < E) {
            int d = dst[e];
            int s = src[e];
            int2 q;
            q.x = s;
            q.y = __float_as_int(dinv[s]);
            csr_sw[rowptr[d] + rank[e]] = q;
        }
    }
}

// ---------------- fused dispatches (block-role striping) ----------------
// Every S-th block is a gemm1 tile; the rest are deg/scatter blocks.
// Independent work overlaps on the CUs within one dispatch (no stream fork
// needed under graph capture).

__global__ __launch_bounds__(256) void k_fuseA(const float* __restrict__ x,
                                               const float* __restrict__ W1,
                                               float* __restrict__ h1,
                                               const int* __restrict__ dst,
                                               int* __restrict__ deg,
                                               int* __restrict__ rank,
                                               int E, int N, int nGemm, int S) {
    int idx = blockIdx.x;
    int k = idx / S, rem = idx % S;
    if (rem == 0 && k < nGemm) {
        gemm1_body(x, W1, h1, k * 64, N);
    } else {
        int cnt = (rem > 0) ? min(k + 1, nGemm) : nGemm;
        deg_body(dst, deg, rank, idx - cnt, E);
    }
}

__global__ __launch_bounds__(256) void k_fuseB(const float* __restrict__ x,
                                               const float* __restrict__ W1,
                                               float* __restrict__ h1,
                                               const int* __restrict__ src,
                                               const int* __restrict__ dst,
                                               const int* __restrict__ rank,
                                               const int* __restrict__ rowptr,
                                               const float* __restrict__ dinv,
                                               int2* __restrict__ csr_sw,
                                               int E, int N, int nGemm, int gemmBase, int S) {
    int idx = blockIdx.x;
    int k = idx / S, rem = idx % S;
    if (rem == 0 && k < nGemm) {
        gemm1_body(x, W1, h1, (gemmBase + k) * 64, N);
    } else {
        int cnt = (rem > 0) ? min(k + 1, nGemm) : nGemm;
        scatter_body(src, dst, rank, rowptr, dinv, csr_sw, idx - cnt, E);
    }
}

// ---------------- agg1 + GEMM2 fused ----------------
// one wave per node, lane = column (H=64).

__global__ __launch_bounds__(256) void k_agg1(const float* __restrict__ h1,
                                              const int* __restrict__ rowptr,
                                              const int2* __restrict__ csr_sw,
                                              const float* __restrict__ dinv,
                                              const float* __restrict__ b1,
                                              const float* __restrict__ W2,
                                              float* __restrict__ h2, int N) {
    int wid = threadIdx.x >> 6;
    int lane = threadIdx.x & 63;
    int n = blockIdx.x * 4 + wid;
    if (n >= N) return;

    float w2r[8];
#pragma unroll
    for (int c = 0; c < 8; ++c) w2r[c] = W2[lane * 8 + c];
    float bias = b1[lane];
    float dn   = dinv[n];
    float self = h1[(size_t)n * 64 + lane];

    int start = __builtin_amdgcn_readfirstlane(rowptr[n]);
    int cnt   = __builtin_amdgcn_readfirstlane(rowptr[n + 1]) - start;
    const int2* qp = csr_sw + start;

    float acc0 = 0.f, acc1 = 0.f;
    int i = 0;
    for (; i + 8 <= cnt; i += 8) {
        int2 q0 = qp[i + 0]; int2 q1 = qp[i + 1];
        int2 q2 = qp[i + 2]; int2 q3 = qp[i + 3];
        int2 q4 = qp[i + 4]; int2 q5 = qp[i + 5];
        int2 q6 = qp[i + 6]; int2 q7 = qp[i + 7];
        float v0 = h1[(size_t)q0.x * 64 + lane];
        float v1 = h1[(size_t)q1.x * 64 + lane];
        float v2 = h1[(size_t)q2.x * 64 + lane];
        float v3 = h1[(size_t)q3.x * 64 + lane];
        float v4 = h1[(size_t)q4.x * 64 + lane];
        float v5 = h1[(size_t)q5.x * 64 + lane];
        float v6 = h1[(size_t)q6.x * 64 + lane];
        float v7 = h1[(size_t)q7.x * 64 + lane];
        acc0 = fmaf(__int_as_float(q0.y), v0, acc0);
        acc1 = fmaf(__int_as_float(q1.y), v1, acc1);
        acc0 = fmaf(__int_as_float(q2.y), v2, acc0);
        acc1 = fmaf(__int_as_float(q3.y), v3, acc1);
        acc0 = fmaf(__int_as_float(q4.y), v4, acc0);
        acc1 = fmaf(__int_as_float(q5.y), v5, acc1);
        acc0 = fmaf(__int_as_float(q6.y), v6, acc0);
        acc1 = fmaf(__int_as_float(q7.y), v7, acc1);
    }
    for (; i < cnt; ++i) {
        int2 q = qp[i];
        acc0 = fmaf(__int_as_float(q.y), h1[(size_t)q.x * 64 + lane], acc0);
    }

    float r = fmaxf(dn * ((acc0 + acc1) + dn * self) + bias, 0.f);

    // fused GEMM2: 8 wave-wide butterfly reductions
    float keep = 0.f;
#pragma unroll
    for (int c = 0; c < 8; ++c) {
        float s = r * w2r[c];
#pragma unroll
        for (int k = 1; k < 64; k <<= 1) s += __shfl_xor(s, k, 64);
        keep = ((lane & 7) == c) ? s : keep;
    }
    if (lane < 8) h2[(size_t)n * 8 + lane] = keep;
}

// ---------------- agg2 ----------------

__global__ __launch_bounds__(256) void k_agg2(const float* __restrict__ h2,
                                              const int* __restrict__ rowptr,
                                              const int2* __restrict__ csr_sw,
                                              const float* __restrict__ dinv,
                                              const float* __restrict__ b2,
                                              float* __restrict__ out, int N) {
    int wid = threadIdx.x >> 6;
    int lane = threadIdx.x & 63;
    int n = blockIdx.x * 4 + wid;
    if (n >= N) return;
    int start = rowptr[n];
    int cnt = rowptr[n + 1] - start;
    int c = lane & 7;
    int ii = lane >> 3;

    float a0 = 0.f, a1 = 0.f;
    int i = ii;
    for (; i + 8 < cnt; i += 16) {
        int2 q0 = csr_sw[start + i];
        int2 q1 = csr_sw[start + i + 8];
        float v0 = h2[(size_t)q0.x * 8 + c];
        float v1 = h2[(size_t)q1.x * 8 + c];
        a0 = fmaf(__int_as_float(q0.y), v0, a0);
        a1 = fmaf(__int_as_float(q1.y), v1, a1);
    }
    if (i < cnt) {
        int2 q = csr_sw[start + i];
        a0 = fmaf(__int_as_float(q.y), h2[(size_t)q.x * 8 + c], a0);
    }
    float acc = a0 + a1;
    acc += __shfl_xor(acc, 8, 64);
    acc += __shfl_xor(acc, 16, 64);
    acc += __shfl_xor(acc, 32, 64);

    if (lane < 8) {
        float dn = dinv[n];
        out[(size_t)n * 8 + lane] =
            dn * (acc + dn * h2[(size_t)n * 8 + lane]) + b2[lane];
    }
}

// ---------------- host launcher ----------------

extern "C" void kernel_launch(void* const* d_in, const int* in_sizes, int n_in,
                              void* d_out, int out_size, void* d_ws, size_t ws_size,
                              hipStream_t stream) {
    const float* x  = (const float*)d_in[0];
    const int*   ei = (const int*)d_in[1];
    const float* W1 = (const float*)d_in[2];
    const float* b1 = (const float*)d_in[3];
    const float* W2 = (const float*)d_in[4];
    const float* b2 = (const float*)d_in[5];
    float* out = (float*)d_out;

    const int H   = in_sizes[3];            // 64
    const int FIN = in_sizes[2] / H;        // 512
    const int N   = in_sizes[0] / FIN;      // 100000
    const int E   = in_sizes[1] / 2;        // 3200000
    const int* srcA = ei;
    const int* dstA = ei + E;

    char* ws = (char*)d_ws;
    size_t off = 0;
    auto alloc = [&](size_t bytes) -> void* {
        void* p = ws + off;
        off += (bytes + 255) & ~(size_t)255;
        return p;
    };
    int*   deg     = (int*)alloc((size_t)N * 4);
    float* dinv    = (float*)alloc((size_t)N * 4);
    int*   rowptr  = (int*)alloc((size_t)(N + 1) * 4);
    int*   rank    = (int*)alloc((size_t)E * 4);
    int*   bsum    = (int*)alloc(4096);
    int2*  csr_sw  = (int2*)alloc((size_t)E * 8);
    float* h1      = (float*)alloc((size_t)N * 64 * 4);
    float* h2      = (float*)alloc((size_t)N * 8 * 4);
    (void)ws_size; (void)n_in; (void)out_size;

    int nb = (N + 255) / 256;                 // scan blocks (391)
    int nEdgeBlk = (E + 1023) / 1024;         // 4 edges/thread (3125)
    int nGemmTot = (N + 63) / 64;             // 1563
    int nGA = nGemmTot * 3 / 5;               // gemm tiles overlapped with deg
    int nGB = nGemmTot - nGA;                 // gemm tiles overlapped with scatter

    int gridA = nGA + nEdgeBlk;
    int SA = gridA / nGA;                     // stripe period (>=1)
    int gridB = nGB + nEdgeBlk;
    int SB = gridB / nGB;

    k_zero <<<nb, 256, 0, stream>>>(deg, N);
    k_fuseA<<<gridA, 256, 0, stream>>>(x, W1, h1, dstA, deg, rank, E, N, nGA, SA);
    k_scan1<<<nb, 256, 0, stream>>>(deg, rowptr, bsum, N);
    k_scan2<<<1, 512, 0, stream>>>(bsum, nb);
    k_scan3<<<nb, 256, 0, stream>>>(rowptr, bsum, deg, dinv, N, E);
    k_fuseB<<<gridB, 256, 0, stream>>>(x, W1, h1, srcA, dstA, rank, rowptr, dinv,
                                       csr_sw, E, N, nGB, nGA, SB);
    k_agg1 <<<(N + 3) / 4, 256, 0, stream>>>(h1, rowptr, csr_sw, dinv, b1, W2, h2, N);
    k_agg2 <<<(N + 3) / 4, 256, 0, stream>>>(h2, rowptr, csr_sw, dinv, b2, out, N);
}

// Round 5
// 638.240 us; speedup vs baseline: 1.1197x; 1.1197x over previous
//
#include <hip/hip_runtime.h>
#include <cstdint>
#include <cstddef>

// ================= bucket-sort CSR build =================
// Buckets of 128 consecutive node ids. Bucket order == node order, so
// bucket_start doubles as the CSR region start and rowptr is
// bucket_start[b] + local exclusive scan. All per-node atomics are LDS-only.

#define NODE_SHIFT 7
#define NODE_RANGE 128
#define MAX_B 1024           // supports N <= 131072
#define CHUNK 16384          // edges per bcount/bscatter block (64/thread)

__global__ void k_zero(int* __restrict__ p, int n) {
    int i = blockIdx.x * blockDim.x + threadIdx.x;
    if (i < n) p[i] = 0;
}

// per-chunk LDS histogram over buckets; reserve global per-(block,bin) bases
__global__ __launch_bounds__(256) void k_bcount(const int* __restrict__ dst,
                                                int* __restrict__ bucket_cnt,
                                                int* __restrict__ blk_base,
                                                int E, int B) {
    __shared__ int hist[MAX_B];
    int t = threadIdx.x;
    for (int i = t; i < B; i += 256) hist[i] = 0;
    __syncthreads();
    int base = blockIdx.x * CHUNK;
#pragma unroll 8
    for (int j = 0; j < CHUNK / 256; ++j) {
        int e = base + j * 256 + t;
        if (e < E) atomicAdd(&hist[dst[e] >> NODE_SHIFT], 1);
    }
    __syncthreads();
    for (int i = t; i < B; i += 256)
        blk_base[(size_t)blockIdx.x * B + i] = atomicAdd(&bucket_cnt[i], hist[i]);
}

// single-block exclusive scan of bucket counts -> bucket_start[0..B]
__global__ __launch_bounds__(1024) void k_bscan(const int* __restrict__ bucket_cnt,
                                                int* __restrict__ bucket_start,
                                                int* __restrict__ rowptr,
                                                int B, int N) {
    __shared__ int s[1024];
    int t = threadIdx.x;
    int v = (t < B) ? bucket_cnt[t] : 0;
    s[t] = v;
    __syncthreads();
    for (int off = 1; off < 1024; off <<= 1) {
        int add = (t >= off) ? s[t - off] : 0;
        __syncthreads();
        s[t] += add;
        __syncthreads();
    }
    if (t < B) bucket_start[t] = s[t] - v;
    if (t == 1023) {
        bucket_start[B] = s[1023];   // == E
        rowptr[N] = s[1023];
    }
}

// scatter edges into bucket-grouped order via LDS cursors (no global atomics)
__global__ __launch_bounds__(256) void k_bscatter(const int* __restrict__ src,
                                                  const int* __restrict__ dst,
                                                  const int* __restrict__ bucket_start,
                                                  const int* __restrict__ blk_base,
                                                  int2* __restrict__ bucket_edges,
                                                  int E, int B) {
    __shared__ int cur[MAX_B];
    int t = threadIdx.x;
    for (int i = t; i < B; i += 256)
        cur[i] = bucket_start[i] + blk_base[(size_t)blockIdx.x * B + i];
    __syncthreads();
    int base = blockIdx.x * CHUNK;
#pragma unroll 8
    for (int j = 0; j < CHUNK / 256; ++j) {
        int e = base + j * 256 + t;
        if (e < E) {
            int d = dst[e];
            int p = atomicAdd(&cur[d >> NODE_SHIFT], 1);
            int2 q; q.x = src[e]; q.y = d;
            bucket_edges[p] = q;
        }
    }
}

// per-bucket: 128-bin LDS histogram -> rowptr/dinv, then local CSR scatter.
// All writes land in the bucket's own contiguous region (L2-local, full lines).
__global__ __launch_bounds__(256) void k_bfinal(const int2* __restrict__ bucket_edges,
                                                const int* __restrict__ bucket_start,
                                                int* __restrict__ rowptr,
                                                float* __restrict__ dinv,
                                                int* __restrict__ csr_src,
                                                int N) {
    __shared__ int hist[NODE_RANGE];
    __shared__ int sc[NODE_RANGE];
    int t = threadIdx.x;
    int node0 = blockIdx.x * NODE_RANGE;
    int nn = min(NODE_RANGE, N - node0);
    int estart = bucket_start[blockIdx.x];
    int eend   = bucket_start[blockIdx.x + 1];

    if (t < NODE_RANGE) hist[t] = 0;
    __syncthreads();
    for (int e = estart + t; e < eend; e += 256)
        atomicAdd(&hist[bucket_edges[e].y - node0], 1);
    __syncthreads();

    int v = 0;
    if (t < NODE_RANGE) { v = hist[t]; sc[t] = v; }
    __syncthreads();
    for (int off = 1; off < NODE_RANGE; off <<= 1) {
        int add = (t < NODE_RANGE && t >= off) ? sc[t - off] : 0;
        __syncthreads();
        if (t < NODE_RANGE) sc[t] += add;
        __syncthreads();
    }

    int excl = (t < NODE_RANGE) ? (sc[t] - v) : 0;
    if (t < NODE_RANGE) hist[t] = estart + excl;     // becomes the cursor
    if (t < nn) {
        rowptr[node0 + t] = estart + excl;
        dinv[node0 + t] = rsqrtf((float)(v + 1));    // +1 = self-loop
    }
    __syncthreads();

    for (int e = estart + t; e < eend; e += 256) {
        int2 q = bucket_edges[e];
        int slot = atomicAdd(&hist[q.y - node0], 1);
        csr_src[slot] = q.x;
    }
}

// ================= GEMM1: h1[N,64] = x[N,512] @ W1[512,64] =================
// 64x64 tile per block, 256 threads, 4x4 micro-tile, K-chunks of 32.

__global__ __launch_bounds__(256) void k_gemm1(const float* __restrict__ x,
                                               const float* __restrict__ W1,
                                               float* __restrict__ h1, int N) {
    __shared__ float xsT[32][68];
    __shared__ float ws[32][64];
    int t = threadIdx.x;
    int tc = t & 15;
    int tr = t >> 4;
    int row0 = blockIdx.x * 64;

    float acc[4][4] = {{0.f}};

    int lr  = t >> 2;
    int lkq = (t & 3) * 8;

    for (int k0 = 0; k0 < 512; k0 += 32) {
        {
            int gr = row0 + lr;
            float4 v0 = {0.f, 0.f, 0.f, 0.f}, v1 = {0.f, 0.f, 0.f, 0.f};
            if (gr < N) {
                const float* p = x + (size_t)gr * 512 + k0 + lkq;
                v0 = *(const float4*)p;
                v1 = *(const float4*)(p + 4);
            }
            xsT[lkq + 0][lr] = v0.x; xsT[lkq + 1][lr] = v0.y;
            xsT[lkq + 2][lr] = v0.z; xsT[lkq + 3][lr] = v0.w;
            xsT[lkq + 4][lr] = v1.x; xsT[lkq + 5][lr] = v1.y;
            xsT[lkq + 6][lr] = v1.z; xsT[lkq + 7][lr] = v1.w;
        }
        {
            const float* p = W1 + (size_t)k0 * 64 + t * 8;
            float4 v0 = *(const float4*)p;
            float4 v1 = *(const float4*)(p + 4);
            int kk = (t * 8) >> 6;
            int cc = (t * 8) & 63;
            *(float4*)&ws[kk][cc]     = v0;
            *(float4*)&ws[kk][cc + 4] = v1;
        }
        __syncthreads();

#pragma unroll
        for (int kk = 0; kk < 32; ++kk) {
            float4 a = *(const float4*)&xsT[kk][tr * 4];
            float4 b = *(const float4*)&ws[kk][tc * 4];
            acc[0][0] += a.x * b.x; acc[0][1] += a.x * b.y;
            acc[0][2] += a.x * b.z; acc[0][3] += a.x * b.w;
            acc[1][0] += a.y * b.x; acc[1][1] += a.y * b.y;
            acc[1][2] += a.y * b.z; acc[1][3] += a.y * b.w;
            acc[2][0] += a.z * b.x; acc[2][1] += a.z * b.y;
            acc[2][2] += a.z * b.z; acc[2][3] += a.z * b.w;
            acc[3][0] += a.w * b.x; acc[3][1] += a.w * b.y;
            acc[3][2] += a.w * b.z; acc[3][3] += a.w * b.w;
        }
        __syncthreads();
    }

#pragma unroll
    for (int r = 0; r < 4; ++r) {
        int gr = row0 + tr * 4 + r;
        if (gr < N) {
            float4 v = {acc[r][0], acc[r][1], acc[r][2], acc[r][3]};
            *(float4*)&h1[(size_t)gr * 64 + tc * 4] = v;
        }
    }
}

// ================= agg1 + GEMM2 fused =================
// one wave per node, lane = column (H=64).

__global__ __launch_bounds__(256) void k_agg1(const float* __restrict__ h1,
                                              const int* __restrict__ rowptr,
                                              const int* __restrict__ csr_src,
                                              const float* __restrict__ dinv,
                                              const float* __restrict__ b1,
                                              const float* __restrict__ W2,
                                              float* __restrict__ h2, int N) {
    int wid = threadIdx.x >> 6;
    int lane = threadIdx.x & 63;
    int n = blockIdx.x * 4 + wid;
    if (n >= N) return;

    float w2r[8];
#pragma unroll
    for (int c = 0; c < 8; ++c) w2r[c] = W2[lane * 8 + c];
    float bias = b1[lane];
    float dn   = dinv[n];
    float self = h1[(size_t)n * 64 + lane];

    int start = __builtin_amdgcn_readfirstlane(rowptr[n]);
    int cnt   = __builtin_amdgcn_readfirstlane(rowptr[n + 1]) - start;
    const int* qp = csr_src + start;

    float acc0 = 0.f, acc1 = 0.f;
    int i = 0;
    for (; i + 8 <= cnt; i += 8) {
        int q0 = qp[i + 0]; int q1 = qp[i + 1];
        int q2 = qp[i + 2]; int q3 = qp[i + 3];
        int q4 = qp[i + 4]; int q5 = qp[i + 5];
        int q6 = qp[i + 6]; int q7 = qp[i + 7];
        float w0 = dinv[q0]; float w1 = dinv[q1];
        float w2 = dinv[q2]; float w3 = dinv[q3];
        float w4 = dinv[q4]; float w5 = dinv[q5];
        float w6 = dinv[q6]; float w7 = dinv[q7];
        float v0 = h1[(size_t)q0 * 64 + lane];
        float v1 = h1[(size_t)q1 * 64 + lane];
        float v2 = h1[(size_t)q2 * 64 + lane];
        float v3 = h1[(size_t)q3 * 64 + lane];
        float v4 = h1[(size_t)q4 * 64 + lane];
        float v5 = h1[(size_t)q5 * 64 + lane];
        float v6 = h1[(size_t)q6 * 64 + lane];
        float v7 = h1[(size_t)q7 * 64 + lane];
        acc0 = fmaf(w0, v0, acc0);
        acc1 = fmaf(w1, v1, acc1);
        acc0 = fmaf(w2, v2, acc0);
        acc1 = fmaf(w3, v3, acc1);
        acc0 = fmaf(w4, v4, acc0);
        acc1 = fmaf(w5, v5, acc1);
        acc0 = fmaf(w6, v6, acc0);
        acc1 = fmaf(w7, v7, acc1);
    }
    for (; i < cnt; ++i) {
        int q = qp[i];
        acc0 = fmaf(dinv[q], h1[(size_t)q * 64 + lane], acc0);
    }

    float r = fmaxf(dn * ((acc0 + acc1) + dn * self) + bias, 0.f);

    // fused GEMM2: 8 wave-wide butterfly reductions
    float keep = 0.f;
#pragma unroll
    for (int c = 0; c < 8; ++c) {
        float s = r * w2r[c];
#pragma unroll
        for (int k = 1; k < 64; k <<= 1) s += __shfl_xor(s, k, 64);
        keep = ((lane & 7) == c) ? s : keep;
    }
    if (lane < 8) h2[(size_t)n * 8 + lane] = keep;
}

// ================= agg2 =================

__global__ __launch_bounds__(256) void k_agg2(const float* __restrict__ h2,
                                              const int* __restrict__ rowptr,
                                              const int* __restrict__ csr_src,
                                              const float* __restrict__ dinv,
                                              const float* __restrict__ b2,
                                              float* __restrict__ out, int N) {
    int wid = threadIdx.x >> 6;
    int lane = threadIdx.x & 63;
    int n = blockIdx.x * 4 + wid;
    if (n >= N) return;
    int start = rowptr[n];
    int cnt = rowptr[n + 1] - start;
    int c = lane & 7;
    int ii = lane >> 3;

    float a0 = 0.f, a1 = 0.f;
    int i = ii;
    for (; i + 8 < cnt; i += 16) {
        int q0 = csr_src[start + i];
        int q1 = csr_src[start + i + 8];
        float w0 = dinv[q0], w1 = dinv[q1];
        float v0 = h2[(size_t)q0 * 8 + c];
        float v1 = h2[(size_t)q1 * 8 + c];
        a0 = fmaf(w0, v0, a0);
        a1 = fmaf(w1, v1, a1);
    }
    if (i < cnt) {
        int q = csr_src[start + i];
        a0 = fmaf(dinv[q], h2[(size_t)q * 8 + c], a0);
    }
    float acc = a0 + a1;
    acc += __shfl_xor(acc, 8, 64);
    acc += __shfl_xor(acc, 16, 64);
    acc += __shfl_xor(acc, 32, 64);

    if (lane < 8) {
        float dn = dinv[n];
        out[(size_t)n * 8 + lane] =
            dn * (acc + dn * h2[(size_t)n * 8 + lane]) + b2[lane];
    }
}

// ================= host launcher =================

extern "C" void kernel_launch(void* const* d_in, const int* in_sizes, int n_in,
                              void* d_out, int out_size, void* d_ws, size_t ws_size,
                              hipStream_t stream) {
    const float* x  = (const float*)d_in[0];
    const int*   ei = (const int*)d_in[1];
    const float* W1 = (const float*)d_in[2];
    const float* b1 = (const float*)d_in[3];
    const float* W2 = (const float*)d_in[4];
    const float* b2 = (const float*)d_in[5];
    float* out = (float*)d_out;

    const int H   = in_sizes[3];            // 64
    const int FIN = in_sizes[2] / H;        // 512
    const int N   = in_sizes[0] / FIN;      // 100000
    const int E   = in_sizes[1] / 2;        // 3200000
    const int* srcA = ei;
    const int* dstA = ei + E;

    const int B    = (N + NODE_RANGE - 1) >> NODE_SHIFT;   // 782
    const int nCnt = (E + CHUNK - 1) / CHUNK;              // 196

    char* ws = (char*)d_ws;
    size_t off = 0;
    auto alloc = [&](size_t bytes) -> void* {
        void* p = ws + off;
        off += (bytes + 255) & ~(size_t)255;
        return p;
    };
    int*   bucket_cnt   = (int*)alloc((size_t)B * 4);
    int*   bucket_start = (int*)alloc((size_t)(B + 1) * 4);
    int*   blk_base     = (int*)alloc((size_t)nCnt * B * 4);
    int2*  bucket_edges = (int2*)alloc((size_t)E * 8);
    int*   csr_src      = (int*)alloc((size_t)E * 4);
    int*   rowptr       = (int*)alloc((size_t)(N + 1) * 4);
    float* dinv         = (float*)alloc((size_t)N * 4);
    float* h1           = (float*)alloc((size_t)N * 64 * 4);
    float* h2           = (float*)alloc((size_t)N * 8 * 4);
    (void)ws_size; (void)n_in; (void)out_size;

    k_zero    <<<(B + 255) / 256, 256, 0, stream>>>(bucket_cnt, B);
    k_bcount  <<<nCnt, 256, 0, stream>>>(dstA, bucket_cnt, blk_base, E, B);
    k_bscan   <<<1, 1024, 0, stream>>>(bucket_cnt, bucket_start, rowptr, B, N);
    k_bscatter<<<nCnt, 256, 0, stream>>>(srcA, dstA, bucket_start, blk_base,
                                         bucket_edges, E, B);
    k_bfinal  <<<B, 256, 0, stream>>>(bucket_edges, bucket_start, rowptr, dinv,
                                      csr_src, N);
    k_gemm1   <<<(N + 63) / 64, 256, 0, stream>>>(x, W1, h1, N);
    k_agg1    <<<(N + 3) / 4, 256, 0, stream>>>(h1, rowptr, csr_src, dinv, b1, W2, h2, N);
    k_agg2    <<<(N + 3) / 4, 256, 0, stream>>>(h2, rowptr, csr_src, dinv, b2, out, N);
}

// Round 6
// 597.379 us; speedup vs baseline: 1.1963x; 1.0684x over previous
//
#include <hip/hip_runtime.h>
#include <cstdint>
#include <cstddef>

// ================= bucket-sort CSR build =================
// Buckets of 128 consecutive node ids. Bucket order == node order, so
// bucket_start doubles as the CSR region start and rowptr is
// bucket_start[b] + local exclusive scan. All per-node atomics are LDS-only.
// Bucket edges are packed: src in bits [0,25), local dst in bits [25,32).

#define NODE_SHIFT 7
#define NODE_RANGE 128
#define MAX_B 1024           // supports N <= 131072 (and N < 2^25 for packing)
#define CHUNK 16384          // edges per bcount/bscatter block (64/thread)

__device__ __forceinline__ unsigned short f2bf(float f) {
    unsigned u = __float_as_uint(f);
    u += 0x7FFFu + ((u >> 16) & 1u);       // round-to-nearest-even
    return (unsigned short)(u >> 16);
}
__device__ __forceinline__ float bf2f(unsigned short h) {
    return __uint_as_float((unsigned)h << 16);
}

__global__ void k_zero(int* __restrict__ p, int n) {
    int i = blockIdx.x * blockDim.x + threadIdx.x;
    if (i < n) p[i] = 0;
}

// per-chunk LDS histogram over buckets; reserve global per-(block,bin) bases
__global__ __launch_bounds__(256) void k_bcount(const int* __restrict__ dst,
                                                int* __restrict__ bucket_cnt,
                                                int* __restrict__ blk_base,
                                                int E, int B) {
    __shared__ int hist[MAX_B];
    int t = threadIdx.x;
    for (int i = t; i < B; i += 256) hist[i] = 0;
    __syncthreads();
    int base = blockIdx.x * CHUNK;
#pragma unroll 8
    for (int j = 0; j < CHUNK / 256; ++j) {
        int e = base + j * 256 + t;
        if (e < E) atomicAdd(&hist[dst[e] >> NODE_SHIFT], 1);
    }
    __syncthreads();
    for (int i = t; i < B; i += 256)
        blk_base[(size_t)blockIdx.x * B + i] = atomicAdd(&bucket_cnt[i], hist[i]);
}

// single-block exclusive scan of bucket counts -> bucket_start[0..B]
__global__ __launch_bounds__(1024) void k_bscan(const int* __restrict__ bucket_cnt,
                                                int* __restrict__ bucket_start,
                                                int* __restrict__ rowptr,
                                                int B, int N) {
    __shared__ int s[1024];
    int t = threadIdx.x;
    int v = (t < B) ? bucket_cnt[t] : 0;
    s[t] = v;
    __syncthreads();
    for (int off = 1; off < 1024; off <<= 1) {
        int add = (t >= off) ? s[t - off] : 0;
        __syncthreads();
        s[t] += add;
        __syncthreads();
    }
    if (t < B) bucket_start[t] = s[t] - v;
    if (t == 1023) {
        bucket_start[B] = s[1023];   // == E
        rowptr[N] = s[1023];
    }
}

// scatter edges into bucket-grouped order via LDS cursors (no global atomics)
__global__ __launch_bounds__(256) void k_bscatter(const int* __restrict__ src,
                                                  const int* __restrict__ dst,
                                                  const int* __restrict__ bucket_start,
                                                  const int* __restrict__ blk_base,
                                                  unsigned* __restrict__ bucket_pk,
                                                  int E, int B) {
    __shared__ int cur[MAX_B];
    int t = threadIdx.x;
    for (int i = t; i < B; i += 256)
        cur[i] = bucket_start[i] + blk_base[(size_t)blockIdx.x * B + i];
    __syncthreads();
    int base = blockIdx.x * CHUNK;
#pragma unroll 8
    for (int j = 0; j < CHUNK / 256; ++j) {
        int e = base + j * 256 + t;
        if (e < E) {
            int d = dst[e];
            int p = atomicAdd(&cur[d >> NODE_SHIFT], 1);
            bucket_pk[p] = (unsigned)src[e] | ((unsigned)(d & (NODE_RANGE - 1)) << 25);
        }
    }
}

// per-bucket: 128-bin LDS histogram -> rowptr/dinv, then local CSR scatter.
// All writes land in the bucket's own contiguous region (L2-local, full lines).
__global__ __launch_bounds__(256) void k_bfinal(const unsigned* __restrict__ bucket_pk,
                                                const int* __restrict__ bucket_start,
                                                int* __restrict__ rowptr,
                                                float* __restrict__ dinv,
                                                int* __restrict__ csr_src,
                                                int N) {
    __shared__ int hist[NODE_RANGE];
    __shared__ int sc[NODE_RANGE];
    int t = threadIdx.x;
    int node0 = blockIdx.x * NODE_RANGE;
    int nn = min(NODE_RANGE, N - node0);
    int estart = bucket_start[blockIdx.x];
    int eend   = bucket_start[blockIdx.x + 1];

    if (t < NODE_RANGE) hist[t] = 0;
    __syncthreads();
    for (int e = estart + t; e < eend; e += 256)
        atomicAdd(&hist[bucket_pk[e] >> 25], 1);
    __syncthreads();

    int v = 0;
    if (t < NODE_RANGE) { v = hist[t]; sc[t] = v; }
    __syncthreads();
    for (int off = 1; off < NODE_RANGE; off <<= 1) {
        int add = (t < NODE_RANGE && t >= off) ? sc[t - off] : 0;
        __syncthreads();
        if (t < NODE_RANGE) sc[t] += add;
        __syncthreads();
    }

    int excl = (t < NODE_RANGE) ? (sc[t] - v) : 0;
    if (t < NODE_RANGE) hist[t] = estart + excl;     // becomes the cursor
    if (t < nn) {
        rowptr[node0 + t] = estart + excl;
        dinv[node0 + t] = rsqrtf((float)(v + 1));    // +1 = self-loop
    }
    __syncthreads();

    for (int e = estart + t; e < eend; e += 256) {
        unsigned q = bucket_pk[e];
        int slot = atomicAdd(&hist[q >> 25], 1);
        csr_src[slot] = (int)(q & 0x01FFFFFFu);
    }
}

// ================= GEMM1: h1[N,64] = x[N,512] @ W1[512,64]  (bf16 out) =====
// 64x64 tile per block, 256 threads, 4x4 micro-tile, K-chunks of 32.

__global__ __launch_bounds__(256) void k_gemm1(const float* __restrict__ x,
                                               const float* __restrict__ W1,
                                               unsigned short* __restrict__ h1,
                                               int N) {
    __shared__ float xsT[32][68];
    __shared__ float ws[32][64];
    int t = threadIdx.x;
    int tc = t & 15;
    int tr = t >> 4;
    int row0 = blockIdx.x * 64;

    float acc[4][4] = {{0.f}};

    int lr  = t >> 2;
    int lkq = (t & 3) * 8;

    for (int k0 = 0; k0 < 512; k0 += 32) {
        {
            int gr = row0 + lr;
            float4 v0 = {0.f, 0.f, 0.f, 0.f}, v1 = {0.f, 0.f, 0.f, 0.f};
            if (gr < N) {
                const float* p = x + (size_t)gr * 512 + k0 + lkq;
                v0 = *(const float4*)p;
                v1 = *(const float4*)(p + 4);
            }
            xsT[lkq + 0][lr] = v0.x; xsT[lkq + 1][lr] = v0.y;
            xsT[lkq + 2][lr] = v0.z; xsT[lkq + 3][lr] = v0.w;
            xsT[lkq + 4][lr] = v1.x; xsT[lkq + 5][lr] = v1.y;
            xsT[lkq + 6][lr] = v1.z; xsT[lkq + 7][lr] = v1.w;
        }
        {
            const float* p = W1 + (size_t)k0 * 64 + t * 8;
            float4 v0 = *(const float4*)p;
            float4 v1 = *(const float4*)(p + 4);
            int kk = (t * 8) >> 6;
            int cc = (t * 8) & 63;
            *(float4*)&ws[kk][cc]     = v0;
            *(float4*)&ws[kk][cc + 4] = v1;
        }
        __syncthreads();

#pragma unroll
        for (int kk = 0; kk < 32; ++kk) {
            float4 a = *(const float4*)&xsT[kk][tr * 4];
            float4 b = *(const float4*)&ws[kk][tc * 4];
            acc[0][0] += a.x * b.x; acc[0][1] += a.x * b.y;
            acc[0][2] += a.x * b.z; acc[0][3] += a.x * b.w;
            acc[1][0] += a.y * b.x; acc[1][1] += a.y * b.y;
            acc[1][2] += a.y * b.z; acc[1][3] += a.y * b.w;
            acc[2][0] += a.z * b.x; acc[2][1] += a.z * b.y;
            acc[2][2] += a.z * b.z; acc[2][3] += a.z * b.w;
            acc[3][0] += a.w * b.x; acc[3][1] += a.w * b.y;
            acc[3][2] += a.w * b.z; acc[3][3] += a.w * b.w;
        }
        __syncthreads();
    }

#pragma unroll
    for (int r = 0; r < 4; ++r) {
        int gr = row0 + tr * 4 + r;
        if (gr < N) {
            ushort4 o;
            o.x = f2bf(acc[r][0]); o.y = f2bf(acc[r][1]);
            o.z = f2bf(acc[r][2]); o.w = f2bf(acc[r][3]);
            *(ushort4*)&h1[(size_t)gr * 64 + tc * 4] = o;
        }
    }
}

// ================= agg1 + GEMM2 fused =================
// one wave per node, lane = column (H=64). h1 is bf16 (128 B/row gather).

__global__ __launch_bounds__(256) void k_agg1(const unsigned short* __restrict__ h1,
                                              const int* __restrict__ rowptr,
                                              const int* __restrict__ csr_src,
                                              const float* __restrict__ dinv,
                                              const float* __restrict__ b1,
                                              const float* __restrict__ W2,
                                              float* __restrict__ h2, int N) {
    int wid = threadIdx.x >> 6;
    int lane = threadIdx.x & 63;
    int n = blockIdx.x * 4 + wid;
    if (n >= N) return;

    float w2r[8];
#pragma unroll
    for (int c = 0; c < 8; ++c) w2r[c] = W2[lane * 8 + c];
    float bias = b1[lane];
    float dn   = dinv[n];
    float self = bf2f(h1[(size_t)n * 64 + lane]);

    int start = __builtin_amdgcn_readfirstlane(rowptr[n]);
    int cnt   = __builtin_amdgcn_readfirstlane(rowptr[n + 1]) - start;
    const int* qp = csr_src + start;

    float acc0 = 0.f, acc1 = 0.f;
    int i = 0;
    for (; i + 8 <= cnt; i += 8) {
        int q0 = qp[i + 0]; int q1 = qp[i + 1];
        int q2 = qp[i + 2]; int q3 = qp[i + 3];
        int q4 = qp[i + 4]; int q5 = qp[i + 5];
        int q6 = qp[i + 6]; int q7 = qp[i + 7];
        float w0 = dinv[q0]; float w1 = dinv[q1];
        float w2 = dinv[q2]; float w3 = dinv[q3];
        float w4 = dinv[q4]; float w5 = dinv[q5];
        float w6 = dinv[q6]; float w7 = dinv[q7];
        float v0 = bf2f(h1[(size_t)q0 * 64 + lane]);
        float v1 = bf2f(h1[(size_t)q1 * 64 + lane]);
        float v2 = bf2f(h1[(size_t)q2 * 64 + lane]);
        float v3 = bf2f(h1[(size_t)q3 * 64 + lane]);
        float v4 = bf2f(h1[(size_t)q4 * 64 + lane]);
        float v5 = bf2f(h1[(size_t)q5 * 64 + lane]);
        float v6 = bf2f(h1[(size_t)q6 * 64 + lane]);
        float v7 = bf2f(h1[(size_t)q7 * 64 + lane]);
        acc0 = fmaf(w0, v0, acc0);
        acc1 = fmaf(w1, v1, acc1);
        acc0 = fmaf(w2, v2, acc0);
        acc1 = fmaf(w3, v3, acc1);
        acc0 = fmaf(w4, v4, acc0);
        acc1 = fmaf(w5, v5, acc1);
        acc0 = fmaf(w6, v6, acc0);
        acc1 = fmaf(w7, v7, acc1);
    }
    for (; i < cnt; ++i) {
        int q = qp[i];
        acc0 = fmaf(dinv[q], bf2f(h1[(size_t)q * 64 + lane]), acc0);
    }

    float r = fmaxf(dn * ((acc0 + acc1) + dn * self) + bias, 0.f);

    // fused GEMM2: 8 wave-wide butterfly reductions
    float keep = 0.f;
#pragma unroll
    for (int c = 0; c < 8; ++c) {
        float s = r * w2r[c];
#pragma unroll
        for (int k = 1; k < 64; k <<= 1) s += __shfl_xor(s, k, 64);
        keep = ((lane & 7) == c) ? s : keep;
    }
    if (lane < 8) h2[(size_t)n * 8 + lane] = keep;
}

// ================= agg2 =================

__global__ __launch_bounds__(256) void k_agg2(const float* __restrict__ h2,
                                              const int* __restrict__ rowptr,
                                              const int* __restrict__ csr_src,
                                              const float* __restrict__ dinv,
                                              const float* __restrict__ b2,
                                              float* __restrict__ out, int N) {
    int wid = threadIdx.x >> 6;
    int lane = threadIdx.x & 63;
    int n = blockIdx.x * 4 + wid;
    if (n >= N) return;
    int start = rowptr[n];
    int cnt = rowptr[n + 1] - start;
    int c = lane & 7;
    int ii = lane >> 3;

    float a0 = 0.f, a1 = 0.f;
    int i = ii;
    for (; i + 8 < cnt; i += 16) {
        int q0 = csr_src[start + i];
        int q1 = csr_src[start + i + 8];
        float w0 = dinv[q0], w1 = dinv[q1];
        float v0 = h2[(size_t)q0 * 8 + c];
        float v1 = h2[(size_t)q1 * 8 + c];
        a0 = fmaf(w0, v0, a0);
        a1 = fmaf(w1, v1, a1);
    }
    if (i < cnt) {
        int q = csr_src[start + i];
        a0 = fmaf(dinv[q], h2[(size_t)q * 8 + c], a0);
    }
    float acc = a0 + a1;
    acc += __shfl_xor(acc, 8, 64);
    acc += __shfl_xor(acc, 16, 64);
    acc += __shfl_xor(acc, 32, 64);

    if (lane < 8) {
        float dn = dinv[n];
        out[(size_t)n * 8 + lane] =
            dn * (acc + dn * h2[(size_t)n * 8 + lane]) + b2[lane];
    }
}

// ================= host launcher =================

extern "C" void kernel_launch(void* const* d_in, const int* in_sizes, int n_in,
                              void* d_out, int out_size, void* d_ws, size_t ws_size,
                              hipStream_t stream) {
    const float* x  = (const float*)d_in[0];
    const int*   ei = (const int*)d_in[1];
    const float* W1 = (const float*)d_in[2];
    const float* b1 = (const float*)d_in[3];
    const float* W2 = (const float*)d_in[4];
    const float* b2 = (const float*)d_in[5];
    float* out = (float*)d_out;

    const int H   = in_sizes[3];            // 64
    const int FIN = in_sizes[2] / H;        // 512
    const int N   = in_sizes[0] / FIN;      // 100000
    const int E   = in_sizes[1] / 2;        // 3200000
    const int* srcA = ei;
    const int* dstA = ei + E;

    const int B    = (N + NODE_RANGE - 1) >> NODE_SHIFT;   // 782
    const int nCnt = (E + CHUNK - 1) / CHUNK;              // 196

    char* ws = (char*)d_ws;
    size_t off = 0;
    auto alloc = [&](size_t bytes) -> void* {
        void* p = ws + off;
        off += (bytes + 255) & ~(size_t)255;
        return p;
    };
    int*      bucket_cnt   = (int*)alloc((size_t)B * 4);
    int*      bucket_start = (int*)alloc((size_t)(B + 1) * 4);
    int*      blk_base     = (int*)alloc((size_t)nCnt * B * 4);
    unsigned* bucket_pk    = (unsigned*)alloc((size_t)E * 4);
    int*      csr_src      = (int*)alloc((size_t)E * 4);
    int*      rowptr       = (int*)alloc((size_t)(N + 1) * 4);
    float*    dinv         = (float*)alloc((size_t)N * 4);
    unsigned short* h1     = (unsigned short*)alloc((size_t)N * 64 * 2);
    float*    h2           = (float*)alloc((size_t)N * 8 * 4);
    (void)ws_size; (void)n_in; (void)out_size;

    k_zero    <<<(B + 255) / 256, 256, 0, stream>>>(bucket_cnt, B);
    k_bcount  <<<nCnt, 256, 0, stream>>>(dstA, bucket_cnt, blk_base, E, B);
    k_bscan   <<<1, 1024, 0, stream>>>(bucket_cnt, bucket_start, rowptr, B, N);
    k_bscatter<<<nCnt, 256, 0, stream>>>(srcA, dstA, bucket_start, blk_base,
                                         bucket_pk, E, B);
    k_bfinal  <<<B, 256, 0, stream>>>(bucket_pk, bucket_start, rowptr, dinv,
                                      csr_src, N);
    k_gemm1   <<<(N + 63) / 64, 256, 0, stream>>>(x, W1, h1, N);
    k_agg1    <<<(N + 3) / 4, 256, 0, stream>>>(h1, rowptr, csr_src, dinv, b1, W2, h2, N);
    k_agg2    <<<(N + 3) / 4, 256, 0, stream>>>(h2, rowptr, csr_src, dinv, b2, out, N);
}